// Round 3
// baseline (2018.420 us; speedup 1.0000x reference)
//
#include <hip/hip_runtime.h>
#include <math.h>

typedef unsigned short ushort_t;
typedef __attribute__((ext_vector_type(8))) short bf16x8;
typedef __attribute__((ext_vector_type(4))) float f32x4;
typedef __attribute__((ext_vector_type(8))) unsigned short us8;

typedef __attribute__((address_space(1))) unsigned int gu32;
typedef __attribute__((address_space(3))) unsigned int lu32;

__device__ __forceinline__ void gload16(const void* g, void* l) {
    __builtin_amdgcn_global_load_lds((const gu32*)g, (lu32*)l, 16, 0, 0);
}

__device__ __forceinline__ unsigned short f2bf(float f) {
    unsigned u = __float_as_uint(f);
    unsigned r = ((u >> 16) & 1u) + 0x7fffu;
    return (unsigned short)((u + r) >> 16);
}

// ---------------- workspace layout (float offsets) ----------------
#define HB_OFF   0ULL           // hb  [64][64][64][64] bf16   (8,388,608 f-slots)
#define WT2_OFF  8388608ULL     // wt2 [81][64][64] bf16       (165,888 f-slots)
#define TMP_OFF  8554496ULL     // tmp [64][784][64] f32        3,211,264
#define UT2_OFF  11765760ULL    // ut2 [6272][64][8] f32        3,211,264
#define S_OFF    14977024ULL    // s   [64][10][16]                10,240
#define V0_OFF   14987264ULL
#define V1_OFF   14997504ULL

// ---------------- conv1: 1->64ch, k5, pad2, +bias, relu -> NHWC bf16 ----------------
__global__ __launch_bounds__(256) void conv1_nhwc_kernel(const float* __restrict__ x,
                                                         const float* __restrict__ w,
                                                         const float* __restrict__ bias,
                                                         ushort_t* __restrict__ hb) {
    int t = blockIdx.x * 256 + threadIdx.x;         // 262144 (b,y,x)
    int xx = t & 63, yy = (t >> 6) & 63, b = t >> 12;
    int cg = blockIdx.y;                            // 0..7
    const float* xb = x + (size_t)b * 4096;
    float xv[25];
    #pragma unroll
    for (int ky = 0; ky < 5; ++ky) {
        int iy = yy + ky - 2;
        #pragma unroll
        for (int kx = 0; kx < 5; ++kx) {
            int ix = xx + kx - 2;
            bool ok = (iy >= 0 && iy < 64 && ix >= 0 && ix < 64);
            xv[ky * 5 + kx] = ok ? xb[iy * 64 + ix] : 0.f;
        }
    }
    us8 o;
    #pragma unroll
    for (int cc = 0; cc < 8; ++cc) {
        int c = cg * 8 + cc;
        float acc = bias[c];
        const float* wc = w + c * 25;
        #pragma unroll
        for (int k = 0; k < 25; ++k) acc = fmaf(xv[k], wc[k], acc);
        o[cc] = f2bf(fmaxf(acc, 0.f));
    }
    *(us8*)&hb[(size_t)t * 64 + cg * 8] = o;
}

// ---------------- conv2 weight transform: pw[c][ic][9][9] f32 -> wt2[p][c][ic] bf16 --------
__global__ __launch_bounds__(256) void wt2_transform_kernel(const float* __restrict__ pw,
                                                            ushort_t* __restrict__ wt2) {
    int t = blockIdx.x * 256 + threadIdx.x;         // 331776
    int ic = t & 63, c = (t >> 6) & 63, p = t >> 12;
    wt2[t] = f2bf(pw[(size_t)(c * 64 + ic) * 81 + p]);
}

// ---------------- conv2 implicit-GEMM MFMA: 64->64, k9, s2, +bias ----------------
__global__ __launch_bounds__(256) void conv2_mfma_kernel(const ushort_t* __restrict__ hb,
                                                         const ushort_t* __restrict__ wt2,
                                                         const float* __restrict__ pb,
                                                         float* __restrict__ tmp) {
    __shared__ ushort_t As[2][4096];
    __shared__ ushort_t Bs[2][4096];

    int tid = threadIdx.x;
    int w = tid >> 6, lane = tid & 63;
    int m0 = blockIdx.x * 64;

    int srow = w * 16 + (lane >> 3);
    int srcchunk = (lane & 7) ^ ((lane >> 3) & 7);
    unsigned gbaseA[2];
    #pragma unroll
    for (int k = 0; k < 2; ++k) {
        int r = srow + k * 8;
        int m = m0 + r;
        int b = m / 784, pos = m % 784;
        int oy = pos / 28, ox = pos % 28;
        gbaseA[k] = ((unsigned)((b * 64 + 2 * oy) * 64 + 2 * ox)) * 64 + srcchunk * 8;
    }
    unsigned gbaseB[2] = { (unsigned)srow * 64 + srcchunk * 8,
                           (unsigned)(srow + 8) * 64 + srcchunk * 8 };

    int fr = lane & 15, fq = lane >> 4;
    int rlow = fr & 7;
    int c0 = (fq ^ rlow) * 8;
    int c1 = ((4 + fq) ^ rlow) * 8;
    int rowA = w * 16 + fr;
    int offA0 = rowA * 64 + c0, offA1 = rowA * 64 + c1;
    int offB0[4], offB1[4];
    #pragma unroll
    for (int jf = 0; jf < 4; ++jf) {
        int rowB = jf * 16 + fr;
        offB0[jf] = rowB * 64 + c0;
        offB1[jf] = rowB * 64 + c1;
    }

    f32x4 acc[4] = {};

    auto stage = [&](int p, int buf) {
        int ky = p / 9, kx = p % 9;
        unsigned koff = (unsigned)(ky * 4096 + kx * 64);
        unsigned boff = (unsigned)p * 4096;
        gload16(hb + gbaseA[0] + koff, &As[buf][w * 1024]);
        gload16(hb + gbaseA[1] + koff, &As[buf][w * 1024 + 512]);
        gload16(wt2 + boff + gbaseB[0], &Bs[buf][w * 1024]);
        gload16(wt2 + boff + gbaseB[1], &Bs[buf][w * 1024 + 512]);
    };

    stage(0, 0);
    __syncthreads();

    for (int p = 0; p < 81; ++p) {
        int cur = p & 1;
        const ushort_t* A = As[cur];
        const ushort_t* B = Bs[cur];
        bf16x8 a0 = *(const bf16x8*)&A[offA0];
        bf16x8 a1 = *(const bf16x8*)&A[offA1];
        bf16x8 b0[4], b1[4];
        #pragma unroll
        for (int jf = 0; jf < 4; ++jf) {
            b0[jf] = *(const bf16x8*)&B[offB0[jf]];
            b1[jf] = *(const bf16x8*)&B[offB1[jf]];
        }
        #pragma unroll
        for (int jf = 0; jf < 4; ++jf)
            acc[jf] = __builtin_amdgcn_mfma_f32_16x16x32_bf16(a0, b0[jf], acc[jf], 0, 0, 0);
        #pragma unroll
        for (int jf = 0; jf < 4; ++jf)
            acc[jf] = __builtin_amdgcn_mfma_f32_16x16x32_bf16(a1, b1[jf], acc[jf], 0, 0, 0);
        if (p < 80) stage(p + 1, cur ^ 1);
        __syncthreads();
    }

    #pragma unroll
    for (int jf = 0; jf < 4; ++jf) {
        int n = jf * 16 + fr;
        float bv = pb[n];
        #pragma unroll
        for (int reg = 0; reg < 4; ++reg) {
            int m = w * 16 + fq * 4 + reg;
            tmp[(size_t)(m0 + m) * 64 + n] = acc[jf][reg] + bv;
        }
    }
}

// ---------------- squash u -> ut2[n][b][j] ----------------
__global__ __launch_bounds__(256) void squash_u_kernel(const float* __restrict__ tmp,
                                                       float* __restrict__ ut2) {
    int idx = blockIdx.x * 256 + threadIdx.x;      // 401,408 = 6272*64
    int b = idx & 63;
    int n = idx >> 6;
    int caps = n / 784, pos = n % 784;
    const float* tp = tmp + ((size_t)b * 784 + pos) * 64 + caps * 8;
    float v[8]; float msq = 0.f;
    #pragma unroll
    for (int j = 0; j < 8; ++j) { v[j] = tp[j]; msq = fmaf(v[j], v[j], msq); }
    float mag = sqrtf(msq + 1e-9f);
    float sc = msq / (1.f + msq) / (mag + 1e-9f);
    float* op = ut2 + (size_t)idx * 8;
    #pragma unroll
    for (int j = 0; j < 8; ++j) op[j] = v[j] * sc;
}

// ---------------- routing: lane = batch, W wave-uniform (scalar loads) ----------------
// grid: 392 blocks x 4 waves; each wave handles NW=4 routes n for all 64 batches.
#define NW 4
template<int ITER>
__global__ __launch_bounds__(256, 2) void routing2_kernel(const float* __restrict__ W,
                                                          const float* __restrict__ ut2,
                                                          const float* __restrict__ v0,
                                                          const float* __restrict__ v1,
                                                          float* __restrict__ s) {
    __shared__ float vs[64][161];   // ITER>=1: v-sum staging; later reused for s-reduce
    int tid = threadIdx.x;
    int b = tid & 63;               // lane = batch
    int wid = __builtin_amdgcn_readfirstlane(tid >> 6);

    if (ITER >= 1) {
        for (int k = tid; k < 10240; k += 256) {
            int bb = k / 160, oi = k % 160;
            float val = v0[bb * 160 + oi];
            if (ITER == 2) val += v1[bb * 160 + oi];
            vs[bb][oi] = val;
        }
        __syncthreads();
    }

    int n0 = (blockIdx.x * 4 + wid) * NW;

    float acc[160];
    #pragma unroll
    for (int oi = 0; oi < 160; ++oi) acc[oi] = 0.f;

    for (int t = 0; t < NW; ++t) {
        int n = __builtin_amdgcn_readfirstlane(n0 + t);
        const float* wrow = W + (size_t)n * 1280;           // wave-uniform
        const float* up = ut2 + ((size_t)n * 64 + b) * 8;
        float u[8];
        *(f32x4*)&u[0] = *(const f32x4*)&up[0];
        *(f32x4*)&u[4] = *(const f32x4*)&up[4];

        float c[10];
        if (ITER >= 1) {
            float l[10];
            #pragma unroll
            for (int o = 0; o < 10; ++o) {
                float lo = 0.f;
                #pragma unroll
                for (int i = 0; i < 16; ++i) {
                    const float* wp = wrow + (o * 16 + i) * 8;
                    float uh = 0.f;
                    #pragma unroll
                    for (int j = 0; j < 8; ++j) uh = fmaf(wp[j], u[j], uh);
                    lo = fmaf(uh, vs[b][o * 16 + i], lo);
                }
                l[o] = lo;
            }
            float m = l[0];
            #pragma unroll
            for (int o = 1; o < 10; ++o) m = fmaxf(m, l[o]);
            float sum = 0.f;
            #pragma unroll
            for (int o = 0; o < 10; ++o) { c[o] = __expf(l[o] - m); sum += c[o]; }
            float inv = 1.f / sum;
            #pragma unroll
            for (int o = 0; o < 10; ++o) c[o] *= inv;
        }

        #pragma unroll
        for (int o = 0; o < 10; ++o) {
            float co = (ITER == 0) ? 1.f : c[o];
            #pragma unroll
            for (int i = 0; i < 16; ++i) {
                const float* wp = wrow + (o * 16 + i) * 8;
                float uh = 0.f;
                #pragma unroll
                for (int j = 0; j < 8; ++j) uh = fmaf(wp[j], u[j], uh);
                acc[o * 16 + i] = fmaf(co, uh, acc[o * 16 + i]);
            }
        }
    }

    // block-level reduce across the 4 waves (reuse vs LDS; each lane owns row b)
    __syncthreads();
    #pragma unroll
    for (int w = 0; w < 4; ++w) {
        if (wid == w) {
            if (w == 0) {
                #pragma unroll
                for (int oi = 0; oi < 160; ++oi) vs[b][oi] = acc[oi];
            } else {
                #pragma unroll
                for (int oi = 0; oi < 160; ++oi) vs[b][oi] += acc[oi];
            }
        }
        __syncthreads();
    }
    if (wid == 0) {
        float scale = (ITER == 0) ? 0.1f : 1.f;
        #pragma unroll
        for (int oi = 0; oi < 160; ++oi)
            atomicAdd(&s[b * 160 + oi], vs[b][oi] * scale);
    }
}

// ---------------- squash s -> v ----------------
__global__ void squash_v_kernel(const float* __restrict__ s, float* __restrict__ v) {
    int t = threadIdx.x;
    if (t >= 640) return;
    const float* sp = s + t * 16;
    float val[16]; float msq = 0.f;
    #pragma unroll
    for (int i = 0; i < 16; ++i) { val[i] = sp[i]; msq = fmaf(val[i], val[i], msq); }
    float mag = sqrtf(msq + 1e-9f);
    float sc = msq / (1.f + msq) / (mag + 1e-9f);
    float* vp = v + t * 16;
    #pragma unroll
    for (int i = 0; i < 16; ++i) vp[i] = val[i] * sc;
}

extern "C" void kernel_launch(void* const* d_in, const int* in_sizes, int n_in,
                              void* d_out, int out_size, void* d_ws, size_t ws_size,
                              hipStream_t stream) {
    const float* x  = (const float*)d_in[0];
    const float* w1 = (const float*)d_in[1];
    const float* b1 = (const float*)d_in[2];
    const float* pw = (const float*)d_in[3];
    const float* pb = (const float*)d_in[4];
    const float* W  = (const float*)d_in[5];
    float* out = (float*)d_out;
    float* ws  = (float*)d_ws;

    ushort_t* hb  = (ushort_t*)(ws + HB_OFF);
    ushort_t* wt2 = (ushort_t*)(ws + WT2_OFF);
    float*    tmp = ws + TMP_OFF;
    float*    ut2 = ws + UT2_OFF;
    float*    s   = ws + S_OFF;
    float*    v0  = ws + V0_OFF;
    float*    v1  = ws + V1_OFF;

    conv1_nhwc_kernel<<<dim3(1024, 8), 256, 0, stream>>>(x, w1, b1, hb);
    wt2_transform_kernel<<<1296, 256, 0, stream>>>(pw, wt2);
    conv2_mfma_kernel<<<784, 256, 0, stream>>>(hb, wt2, pb, tmp);
    squash_u_kernel<<<1568, 256, 0, stream>>>(tmp, ut2);

    hipMemsetAsync(s, 0, 10240 * sizeof(float), stream);
    routing2_kernel<0><<<392, 256, 0, stream>>>(W, ut2, nullptr, nullptr, s);
    squash_v_kernel<<<1, 640, 0, stream>>>(s, v0);

    hipMemsetAsync(s, 0, 10240 * sizeof(float), stream);
    routing2_kernel<1><<<392, 256, 0, stream>>>(W, ut2, v0, nullptr, s);
    squash_v_kernel<<<1, 640, 0, stream>>>(s, v1);

    hipMemsetAsync(s, 0, 10240 * sizeof(float), stream);
    routing2_kernel<2><<<392, 256, 0, stream>>>(W, ut2, v0, v1, s);
    squash_v_kernel<<<1, 640, 0, stream>>>(s, out);
}

// Round 4
// 1546.001 us; speedup vs baseline: 1.3056x; 1.3056x over previous
//
#include <hip/hip_runtime.h>
#include <math.h>

typedef unsigned short ushort_t;
typedef __attribute__((ext_vector_type(8))) short bf16x8;
typedef __attribute__((ext_vector_type(4))) float f32x4;
typedef __attribute__((ext_vector_type(8))) unsigned short us8;

typedef __attribute__((address_space(1))) unsigned int gu32;
typedef __attribute__((address_space(3))) unsigned int lu32;

__device__ __forceinline__ void gload16(const void* g, void* l) {
    __builtin_amdgcn_global_load_lds((const gu32*)g, (lu32*)l, 16, 0, 0);
}

__device__ __forceinline__ unsigned short f2bf(float f) {
    unsigned u = __float_as_uint(f);
    unsigned r = ((u >> 16) & 1u) + 0x7fffu;
    return (unsigned short)((u + r) >> 16);
}

// ---------------- workspace layout (float offsets) ----------------
#define HB_OFF   0ULL           // hb  [64][64][64][64] bf16   (8,388,608 f-slots)
#define WT2_OFF  8388608ULL     // wt2 [81][64][64] bf16       (165,888 f-slots)
#define TMP_OFF  8554496ULL     // tmp [64][784][64] f32        3,211,264
#define UT2_OFF  11765760ULL    // ut2 [6272][64][8] f32        3,211,264
#define S_OFF    14977024ULL    // s   [64][10][16]                10,240
#define V0_OFF   14987264ULL
#define V1_OFF   14997504ULL

// ---------------- conv1: 1->64ch, k5, pad2, +bias, relu -> NHWC bf16 ----------------
__global__ __launch_bounds__(256) void conv1_nhwc_kernel(const float* __restrict__ x,
                                                         const float* __restrict__ w,
                                                         const float* __restrict__ bias,
                                                         ushort_t* __restrict__ hb) {
    int t = blockIdx.x * 256 + threadIdx.x;         // 262144 (b,y,x)
    int xx = t & 63, yy = (t >> 6) & 63, b = t >> 12;
    int cg = blockIdx.y;                            // 0..7
    const float* xb = x + (size_t)b * 4096;
    float xv[25];
    #pragma unroll
    for (int ky = 0; ky < 5; ++ky) {
        int iy = yy + ky - 2;
        #pragma unroll
        for (int kx = 0; kx < 5; ++kx) {
            int ix = xx + kx - 2;
            bool ok = (iy >= 0 && iy < 64 && ix >= 0 && ix < 64);
            xv[ky * 5 + kx] = ok ? xb[iy * 64 + ix] : 0.f;
        }
    }
    us8 o;
    #pragma unroll
    for (int cc = 0; cc < 8; ++cc) {
        int c = cg * 8 + cc;
        float acc = bias[c];
        const float* wc = w + c * 25;
        #pragma unroll
        for (int k = 0; k < 25; ++k) acc = fmaf(xv[k], wc[k], acc);
        o[cc] = f2bf(fmaxf(acc, 0.f));
    }
    *(us8*)&hb[(size_t)t * 64 + cg * 8] = o;
}

// ---------------- conv2 weight transform: pw[c][ic][9][9] f32 -> wt2[p][c][ic] bf16 --------
__global__ __launch_bounds__(256) void wt2_transform_kernel(const float* __restrict__ pw,
                                                            ushort_t* __restrict__ wt2) {
    int t = blockIdx.x * 256 + threadIdx.x;         // 331776
    int ic = t & 63, c = (t >> 6) & 63, p = t >> 12;
    wt2[t] = f2bf(pw[(size_t)(c * 64 + ic) * 81 + p]);
}

// ---------------- conv2 implicit-GEMM MFMA: 64->64, k9, s2, +bias ----------------
__global__ __launch_bounds__(256) void conv2_mfma_kernel(const ushort_t* __restrict__ hb,
                                                         const ushort_t* __restrict__ wt2,
                                                         const float* __restrict__ pb,
                                                         float* __restrict__ tmp) {
    __shared__ ushort_t As[2][4096];
    __shared__ ushort_t Bs[2][4096];

    int tid = threadIdx.x;
    int w = tid >> 6, lane = tid & 63;
    int m0 = blockIdx.x * 64;

    int srow = w * 16 + (lane >> 3);
    int srcchunk = (lane & 7) ^ ((lane >> 3) & 7);
    unsigned gbaseA[2];
    #pragma unroll
    for (int k = 0; k < 2; ++k) {
        int r = srow + k * 8;
        int m = m0 + r;
        int b = m / 784, pos = m % 784;
        int oy = pos / 28, ox = pos % 28;
        gbaseA[k] = ((unsigned)((b * 64 + 2 * oy) * 64 + 2 * ox)) * 64 + srcchunk * 8;
    }
    unsigned gbaseB[2] = { (unsigned)srow * 64 + srcchunk * 8,
                           (unsigned)(srow + 8) * 64 + srcchunk * 8 };

    int fr = lane & 15, fq = lane >> 4;
    int rlow = fr & 7;
    int c0 = (fq ^ rlow) * 8;
    int c1 = ((4 + fq) ^ rlow) * 8;
    int rowA = w * 16 + fr;
    int offA0 = rowA * 64 + c0, offA1 = rowA * 64 + c1;
    int offB0[4], offB1[4];
    #pragma unroll
    for (int jf = 0; jf < 4; ++jf) {
        int rowB = jf * 16 + fr;
        offB0[jf] = rowB * 64 + c0;
        offB1[jf] = rowB * 64 + c1;
    }

    f32x4 acc[4] = {};

    auto stage = [&](int p, int buf) {
        int ky = p / 9, kx = p % 9;
        unsigned koff = (unsigned)(ky * 4096 + kx * 64);
        unsigned boff = (unsigned)p * 4096;
        gload16(hb + gbaseA[0] + koff, &As[buf][w * 1024]);
        gload16(hb + gbaseA[1] + koff, &As[buf][w * 1024 + 512]);
        gload16(wt2 + boff + gbaseB[0], &Bs[buf][w * 1024]);
        gload16(wt2 + boff + gbaseB[1], &Bs[buf][w * 1024 + 512]);
    };

    stage(0, 0);
    __syncthreads();

    for (int p = 0; p < 81; ++p) {
        int cur = p & 1;
        const ushort_t* A = As[cur];
        const ushort_t* B = Bs[cur];
        bf16x8 a0 = *(const bf16x8*)&A[offA0];
        bf16x8 a1 = *(const bf16x8*)&A[offA1];
        bf16x8 b0[4], b1[4];
        #pragma unroll
        for (int jf = 0; jf < 4; ++jf) {
            b0[jf] = *(const bf16x8*)&B[offB0[jf]];
            b1[jf] = *(const bf16x8*)&B[offB1[jf]];
        }
        #pragma unroll
        for (int jf = 0; jf < 4; ++jf)
            acc[jf] = __builtin_amdgcn_mfma_f32_16x16x32_bf16(a0, b0[jf], acc[jf], 0, 0, 0);
        #pragma unroll
        for (int jf = 0; jf < 4; ++jf)
            acc[jf] = __builtin_amdgcn_mfma_f32_16x16x32_bf16(a1, b1[jf], acc[jf], 0, 0, 0);
        if (p < 80) stage(p + 1, cur ^ 1);
        __syncthreads();
    }

    #pragma unroll
    for (int jf = 0; jf < 4; ++jf) {
        int n = jf * 16 + fr;
        float bv = pb[n];
        #pragma unroll
        for (int reg = 0; reg < 4; ++reg) {
            int m = w * 16 + fq * 4 + reg;
            tmp[(size_t)(m0 + m) * 64 + n] = acc[jf][reg] + bv;
        }
    }
}

// ---------------- squash u -> ut2[n][b][j] ----------------
__global__ __launch_bounds__(256) void squash_u_kernel(const float* __restrict__ tmp,
                                                       float* __restrict__ ut2) {
    int idx = blockIdx.x * 256 + threadIdx.x;      // 401,408 = 6272*64
    int b = idx & 63;
    int n = idx >> 6;
    int caps = n / 784, pos = n % 784;
    const float* tp = tmp + ((size_t)b * 784 + pos) * 64 + caps * 8;
    float v[8]; float msq = 0.f;
    #pragma unroll
    for (int j = 0; j < 8; ++j) { v[j] = tp[j]; msq = fmaf(v[j], v[j], msq); }
    float mag = sqrtf(msq + 1e-9f);
    float sc = msq / (1.f + msq) / (mag + 1e-9f);
    float* op = ut2 + (size_t)idx * 8;
    #pragma unroll
    for (int j = 0; j < 8; ++j) op[j] = v[j] * sc;
}

// ---------------- routing: lane = batch, wave = i-quad, W wave-uniform ----------------
// grid 392 blocks x 256 threads. Block owns RNB=16 routes; wave w computes
// outputs (o, i=4w..4w+3) for all o -> acc[40] per lane (no spill).
#define RNB 16
template<int ITER>
__global__ __launch_bounds__(256) void routing3_kernel(const float* __restrict__ W,
                                                       const float* __restrict__ ut2,
                                                       const float* __restrict__ v0,
                                                       const float* __restrict__ v1,
                                                       float* __restrict__ s) {
    __shared__ float vs[64][161];          // v-sum staging (ITER>=1 only; DCE'd for ITER0)
    __shared__ float lred[2][4][64][11];   // partial-logit exchange, double-buffered
    int tid = threadIdx.x;
    int b = tid & 63;                                            // lane = batch
    int wu = __builtin_amdgcn_readfirstlane(threadIdx.x >> 6);   // wave = i-quad

    if (ITER >= 1) {
        for (int k = tid; k < 10240; k += 256) {
            float val = v0[k];
            if (ITER == 2) val += v1[k];
            vs[k / 160][k % 160] = val;
        }
        __syncthreads();
    }

    int n0 = blockIdx.x * RNB;

    float acc[40];
    #pragma unroll
    for (int q = 0; q < 40; ++q) acc[q] = 0.f;

    for (int t = 0; t < RNB; ++t) {
        int n = n0 + t;
        const float* wrow = W + (size_t)n * 1280 + wu * 32;      // wave-uniform base
        const float* up = ut2 + ((size_t)n * 64 + b) * 8;
        float u[8];
        *(f32x4*)&u[0] = *(const f32x4*)&up[0];
        *(f32x4*)&u[4] = *(const f32x4*)&up[4];

        float c[10];
        if (ITER >= 1) {
            // partial logits over this wave's 4 i's
            float l[10];
            #pragma unroll
            for (int o = 0; o < 10; ++o) {
                float lo = 0.f;
                #pragma unroll
                for (int ii = 0; ii < 4; ++ii) {
                    const float* wp = wrow + o * 128 + ii * 8;
                    float uh = 0.f;
                    #pragma unroll
                    for (int j = 0; j < 8; ++j) uh = fmaf(wp[j], u[j], uh);
                    lo = fmaf(uh, vs[b][o * 16 + 4 * wu + ii], lo);
                }
                l[o] = lo;
            }
            int p = t & 1;
            #pragma unroll
            for (int o = 0; o < 10; ++o) lred[p][wu][b][o] = l[o];
            __syncthreads();
            #pragma unroll
            for (int o = 0; o < 10; ++o)
                l[o] = ((lred[p][0][b][o] + lred[p][1][b][o]) +
                        (lred[p][2][b][o] + lred[p][3][b][o]));
            float m = l[0];
            #pragma unroll
            for (int o = 1; o < 10; ++o) m = fmaxf(m, l[o]);
            float sum = 0.f;
            #pragma unroll
            for (int o = 0; o < 10; ++o) { c[o] = __expf(l[o] - m); sum += c[o]; }
            float inv = 1.f / sum;
            #pragma unroll
            for (int o = 0; o < 10; ++o) c[o] *= inv;
        }

        // s-accumulate (recompute uh; W row is L1/sL1-hot)
        #pragma unroll
        for (int o = 0; o < 10; ++o) {
            float co = (ITER == 0) ? 1.f : c[o];
            #pragma unroll
            for (int ii = 0; ii < 4; ++ii) {
                const float* wp = wrow + o * 128 + ii * 8;
                float uh = 0.f;
                #pragma unroll
                for (int j = 0; j < 8; ++j) uh = fmaf(wp[j], u[j], uh);
                acc[o * 4 + ii] = fmaf(co, uh, acc[o * 4 + ii]);
            }
        }
    }

    float scale = (ITER == 0) ? 0.1f : 1.f;
    #pragma unroll
    for (int o = 0; o < 10; ++o)
        #pragma unroll
        for (int ii = 0; ii < 4; ++ii)
            atomicAdd(&s[b * 160 + o * 16 + 4 * wu + ii], acc[o * 4 + ii] * scale);
}

// ---------------- squash s -> v ----------------
__global__ void squash_v_kernel(const float* __restrict__ s, float* __restrict__ v) {
    int t = threadIdx.x;
    if (t >= 640) return;
    const float* sp = s + t * 16;
    float val[16]; float msq = 0.f;
    #pragma unroll
    for (int i = 0; i < 16; ++i) { val[i] = sp[i]; msq = fmaf(val[i], val[i], msq); }
    float mag = sqrtf(msq + 1e-9f);
    float sc = msq / (1.f + msq) / (mag + 1e-9f);
    float* vp = v + t * 16;
    #pragma unroll
    for (int i = 0; i < 16; ++i) vp[i] = val[i] * sc;
}

extern "C" void kernel_launch(void* const* d_in, const int* in_sizes, int n_in,
                              void* d_out, int out_size, void* d_ws, size_t ws_size,
                              hipStream_t stream) {
    const float* x  = (const float*)d_in[0];
    const float* w1 = (const float*)d_in[1];
    const float* b1 = (const float*)d_in[2];
    const float* pw = (const float*)d_in[3];
    const float* pb = (const float*)d_in[4];
    const float* W  = (const float*)d_in[5];
    float* out = (float*)d_out;
    float* ws  = (float*)d_ws;

    ushort_t* hb  = (ushort_t*)(ws + HB_OFF);
    ushort_t* wt2 = (ushort_t*)(ws + WT2_OFF);
    float*    tmp = ws + TMP_OFF;
    float*    ut2 = ws + UT2_OFF;
    float*    s   = ws + S_OFF;
    float*    v0  = ws + V0_OFF;
    float*    v1  = ws + V1_OFF;

    conv1_nhwc_kernel<<<dim3(1024, 8), 256, 0, stream>>>(x, w1, b1, hb);
    wt2_transform_kernel<<<1296, 256, 0, stream>>>(pw, wt2);
    conv2_mfma_kernel<<<784, 256, 0, stream>>>(hb, wt2, pb, tmp);
    squash_u_kernel<<<1568, 256, 0, stream>>>(tmp, ut2);

    hipMemsetAsync(s, 0, 10240 * sizeof(float), stream);
    routing3_kernel<0><<<392, 256, 0, stream>>>(W, ut2, nullptr, nullptr, s);
    squash_v_kernel<<<1, 640, 0, stream>>>(s, v0);

    hipMemsetAsync(s, 0, 10240 * sizeof(float), stream);
    routing3_kernel<1><<<392, 256, 0, stream>>>(W, ut2, v0, nullptr, s);
    squash_v_kernel<<<1, 640, 0, stream>>>(s, v1);

    hipMemsetAsync(s, 0, 10240 * sizeof(float), stream);
    routing3_kernel<2><<<392, 256, 0, stream>>>(W, ut2, v0, v1, s);
    squash_v_kernel<<<1, 640, 0, stream>>>(s, out);
}

// Round 5
// 571.148 us; speedup vs baseline: 3.5340x; 2.7068x over previous
//
#include <hip/hip_runtime.h>
#include <math.h>

typedef unsigned short ushort_t;
typedef __attribute__((ext_vector_type(8))) short bf16x8;
typedef __attribute__((ext_vector_type(4))) float f32x4;
typedef __attribute__((ext_vector_type(8))) unsigned short us8;

typedef __attribute__((address_space(1))) unsigned int gu32;
typedef __attribute__((address_space(3))) unsigned int lu32;

__device__ __forceinline__ void gload16(const void* g, void* l) {
    __builtin_amdgcn_global_load_lds((const gu32*)g, (lu32*)l, 16, 0, 0);
}

__device__ __forceinline__ unsigned short f2bf(float f) {
    unsigned u = __float_as_uint(f);
    unsigned r = ((u >> 16) & 1u) + 0x7fffu;
    return (unsigned short)((u + r) >> 16);
}

// ---------------- workspace layout (float offsets) ----------------
#define HB_OFF   0ULL           // hb   [64][64][64][64] bf16   (8,388,608 f-slots)
#define WT2_OFF  8388608ULL     // wt2  [81][64][64] bf16       (165,888 f-slots)
#define TMP_OFF  8554496ULL     // tmp  [64][784][64] f32        3,211,264
#define UT2_OFF  11765760ULL    // ut2  [6272][64][8] f32        3,211,264
#define S_OFF    14977024ULL    // s    [64][10][16]                10,240
#define V0_OFF   14987264ULL
#define V1_OFF   14997504ULL
#define PART_OFF 15007744ULL    // part [784][160][64] f32       8,028,160

// ---------------- conv1: 1->64ch, k5, pad2, +bias, relu -> NHWC bf16 ----------------
__global__ __launch_bounds__(256) void conv1_nhwc_kernel(const float* __restrict__ x,
                                                         const float* __restrict__ w,
                                                         const float* __restrict__ bias,
                                                         ushort_t* __restrict__ hb) {
    int t = blockIdx.x * 256 + threadIdx.x;         // 262144 (b,y,x)
    int xx = t & 63, yy = (t >> 6) & 63, b = t >> 12;
    int cg = blockIdx.y;                            // 0..7
    const float* xb = x + (size_t)b * 4096;
    float xv[25];
    #pragma unroll
    for (int ky = 0; ky < 5; ++ky) {
        int iy = yy + ky - 2;
        #pragma unroll
        for (int kx = 0; kx < 5; ++kx) {
            int ix = xx + kx - 2;
            bool ok = (iy >= 0 && iy < 64 && ix >= 0 && ix < 64);
            xv[ky * 5 + kx] = ok ? xb[iy * 64 + ix] : 0.f;
        }
    }
    us8 o;
    #pragma unroll
    for (int cc = 0; cc < 8; ++cc) {
        int c = cg * 8 + cc;
        float acc = bias[c];
        const float* wc = w + c * 25;
        #pragma unroll
        for (int k = 0; k < 25; ++k) acc = fmaf(xv[k], wc[k], acc);
        o[cc] = f2bf(fmaxf(acc, 0.f));
    }
    *(us8*)&hb[(size_t)t * 64 + cg * 8] = o;
}

// ---------------- conv2 weight transform: pw[c][ic][9][9] f32 -> wt2[p][c][ic] bf16 --------
__global__ __launch_bounds__(256) void wt2_transform_kernel(const float* __restrict__ pw,
                                                            ushort_t* __restrict__ wt2) {
    int t = blockIdx.x * 256 + threadIdx.x;         // 331776
    int ic = t & 63, c = (t >> 6) & 63, p = t >> 12;
    wt2[t] = f2bf(pw[(size_t)(c * 64 + ic) * 81 + p]);
}

// ---------------- conv2 implicit-GEMM MFMA: 64->64, k9, s2, +bias ----------------
__global__ __launch_bounds__(256) void conv2_mfma_kernel(const ushort_t* __restrict__ hb,
                                                         const ushort_t* __restrict__ wt2,
                                                         const float* __restrict__ pb,
                                                         float* __restrict__ tmp) {
    __shared__ ushort_t As[2][4096];
    __shared__ ushort_t Bs[2][4096];

    int tid = threadIdx.x;
    int w = tid >> 6, lane = tid & 63;
    int m0 = blockIdx.x * 64;

    int srow = w * 16 + (lane >> 3);
    int srcchunk = (lane & 7) ^ ((lane >> 3) & 7);
    unsigned gbaseA[2];
    #pragma unroll
    for (int k = 0; k < 2; ++k) {
        int r = srow + k * 8;
        int m = m0 + r;
        int b = m / 784, pos = m % 784;
        int oy = pos / 28, ox = pos % 28;
        gbaseA[k] = ((unsigned)((b * 64 + 2 * oy) * 64 + 2 * ox)) * 64 + srcchunk * 8;
    }
    unsigned gbaseB[2] = { (unsigned)srow * 64 + srcchunk * 8,
                           (unsigned)(srow + 8) * 64 + srcchunk * 8 };

    int fr = lane & 15, fq = lane >> 4;
    int rlow = fr & 7;
    int c0 = (fq ^ rlow) * 8;
    int c1 = ((4 + fq) ^ rlow) * 8;
    int rowA = w * 16 + fr;
    int offA0 = rowA * 64 + c0, offA1 = rowA * 64 + c1;
    int offB0[4], offB1[4];
    #pragma unroll
    for (int jf = 0; jf < 4; ++jf) {
        int rowB = jf * 16 + fr;
        offB0[jf] = rowB * 64 + c0;
        offB1[jf] = rowB * 64 + c1;
    }

    f32x4 acc[4] = {};

    auto stage = [&](int p, int buf) {
        int ky = p / 9, kx = p % 9;
        unsigned koff = (unsigned)(ky * 4096 + kx * 64);
        unsigned boff = (unsigned)p * 4096;
        gload16(hb + gbaseA[0] + koff, &As[buf][w * 1024]);
        gload16(hb + gbaseA[1] + koff, &As[buf][w * 1024 + 512]);
        gload16(wt2 + boff + gbaseB[0], &Bs[buf][w * 1024]);
        gload16(wt2 + boff + gbaseB[1], &Bs[buf][w * 1024 + 512]);
    };

    stage(0, 0);
    __syncthreads();

    for (int p = 0; p < 81; ++p) {
        int cur = p & 1;
        const ushort_t* A = As[cur];
        const ushort_t* B = Bs[cur];
        bf16x8 a0 = *(const bf16x8*)&A[offA0];
        bf16x8 a1 = *(const bf16x8*)&A[offA1];
        bf16x8 b0[4], b1[4];
        #pragma unroll
        for (int jf = 0; jf < 4; ++jf) {
            b0[jf] = *(const bf16x8*)&B[offB0[jf]];
            b1[jf] = *(const bf16x8*)&B[offB1[jf]];
        }
        #pragma unroll
        for (int jf = 0; jf < 4; ++jf)
            acc[jf] = __builtin_amdgcn_mfma_f32_16x16x32_bf16(a0, b0[jf], acc[jf], 0, 0, 0);
        #pragma unroll
        for (int jf = 0; jf < 4; ++jf)
            acc[jf] = __builtin_amdgcn_mfma_f32_16x16x32_bf16(a1, b1[jf], acc[jf], 0, 0, 0);
        if (p < 80) stage(p + 1, cur ^ 1);
        __syncthreads();
    }

    #pragma unroll
    for (int jf = 0; jf < 4; ++jf) {
        int n = jf * 16 + fr;
        float bv = pb[n];
        #pragma unroll
        for (int reg = 0; reg < 4; ++reg) {
            int m = w * 16 + fq * 4 + reg;
            tmp[(size_t)(m0 + m) * 64 + n] = acc[jf][reg] + bv;
        }
    }
}

// ---------------- squash u -> ut2[n][b][j] ----------------
__global__ __launch_bounds__(256) void squash_u_kernel(const float* __restrict__ tmp,
                                                       float* __restrict__ ut2) {
    int idx = blockIdx.x * 256 + threadIdx.x;      // 401,408 = 6272*64
    int b = idx & 63;
    int n = idx >> 6;
    int caps = n / 784, pos = n % 784;
    const float* tp = tmp + ((size_t)b * 784 + pos) * 64 + caps * 8;
    float v[8]; float msq = 0.f;
    #pragma unroll
    for (int j = 0; j < 8; ++j) { v[j] = tp[j]; msq = fmaf(v[j], v[j], msq); }
    float mag = sqrtf(msq + 1e-9f);
    float sc = msq / (1.f + msq) / (mag + 1e-9f);
    float* op = ut2 + (size_t)idx * 8;
    #pragma unroll
    for (int j = 0; j < 8; ++j) op[j] = v[j] * sc;
}

// ---------------- routing: W in LDS (broadcast reads), partial stores (no atomics) ----
// grid 784 blocks x 256 threads. Block owns RPB=8 routes. lane = batch, wave = i-quad.
// Each thread: uh[40] cached, acc[40] partial s for (b, all o, its i-quad).
#define RPB 8
template<int ITER>
__global__ __launch_bounds__(256, 2) void routing4_kernel(const float* __restrict__ W,
                                                          const float* __restrict__ ut2,
                                                          const float* __restrict__ v0,
                                                          const float* __restrict__ v1,
                                                          float* __restrict__ part) {
    __shared__ float Wl[RPB * 1280];       // 40 KB
    __shared__ float lred[2][4][64][11];   // 22.5 KB (ITER>=1 only, else DCE'd)
    int tid = threadIdx.x;
    int b = tid & 63;                                       // lane = batch
    int wu = __builtin_amdgcn_readfirstlane(tid >> 6);      // wave = i-quad
    int n0 = blockIdx.x * RPB;

    // stage W[n0..n0+8) into LDS: 10240 floats via global_load_lds width-16
    {
        const float* src = W + (size_t)n0 * 1280;
        int w64 = (tid >> 6) * 64;                          // wave-uniform lds base
        #pragma unroll
        for (int k = 0; k < 10; ++k)
            gload16(src + (size_t)(k * 256 + tid) * 4, &Wl[(size_t)(k * 256 + w64) * 4]);
    }

    // v-sum for this lane's 40 outputs, in registers
    float vsum[40];
    if (ITER >= 1) {
        #pragma unroll
        for (int o = 0; o < 10; ++o)
            #pragma unroll
            for (int ii = 0; ii < 4; ++ii) {
                int oi = o * 16 + 4 * wu + ii;
                float vv = v0[b * 160 + oi];
                if (ITER == 2) vv += v1[b * 160 + oi];
                vsum[o * 4 + ii] = vv;
            }
    }

    __syncthreads();   // W staged (compiler drains vmcnt before barrier)

    float acc[40];
    #pragma unroll
    for (int q = 0; q < 40; ++q) acc[q] = 0.f;

    #pragma unroll 1
    for (int t = 0; t < RPB; ++t) {
        const float* up = ut2 + ((size_t)(n0 + t) * 64 + b) * 8;
        float u[8];
        *(f32x4*)&u[0] = *(const f32x4*)&up[0];
        *(f32x4*)&u[4] = *(const f32x4*)&up[4];

        const float* wl = &Wl[t * 1280 + wu * 32];          // wave-uniform -> broadcast
        float uh[40];
        #pragma unroll
        for (int o = 0; o < 10; ++o)
            #pragma unroll
            for (int ii = 0; ii < 4; ++ii) {
                const float* wp = wl + o * 128 + ii * 8;
                float h = 0.f;
                #pragma unroll
                for (int j = 0; j < 8; ++j) h = fmaf(wp[j], u[j], h);
                uh[o * 4 + ii] = h;
            }

        float c10[10];
        if (ITER >= 1) {
            float l[10];
            #pragma unroll
            for (int o = 0; o < 10; ++o) {
                float lo = 0.f;
                #pragma unroll
                for (int ii = 0; ii < 4; ++ii)
                    lo = fmaf(uh[o * 4 + ii], vsum[o * 4 + ii], lo);
                l[o] = lo;
            }
            int p = t & 1;
            #pragma unroll
            for (int o = 0; o < 10; ++o) lred[p][wu][b][o] = l[o];
            __syncthreads();
            #pragma unroll
            for (int o = 0; o < 10; ++o)
                l[o] = ((lred[p][0][b][o] + lred[p][1][b][o]) +
                        (lred[p][2][b][o] + lred[p][3][b][o]));
            float m = l[0];
            #pragma unroll
            for (int o = 1; o < 10; ++o) m = fmaxf(m, l[o]);
            float sum = 0.f;
            #pragma unroll
            for (int o = 0; o < 10; ++o) { c10[o] = __expf(l[o] - m); sum += c10[o]; }
            float inv = 1.f / sum;
            #pragma unroll
            for (int o = 0; o < 10; ++o) c10[o] *= inv;
        }

        #pragma unroll
        for (int o = 0; o < 10; ++o) {
            float co = (ITER == 0) ? 1.f : c10[o];
            #pragma unroll
            for (int ii = 0; ii < 4; ++ii)
                acc[o * 4 + ii] = fmaf(co, uh[o * 4 + ii], acc[o * 4 + ii]);
        }
    }

    // coalesced partial store: part[blk][oi][b]
    float* pp = part + (size_t)blockIdx.x * 10240;
    #pragma unroll
    for (int o = 0; o < 10; ++o)
        #pragma unroll
        for (int ii = 0; ii < 4; ++ii)
            pp[(o * 16 + 4 * wu + ii) * 64 + b] = acc[o * 4 + ii];
}

// ---------------- reduce partials -> s ----------------
__global__ __launch_bounds__(256) void reduce_s_kernel(const float* __restrict__ part,
                                                       float* __restrict__ s, float scale) {
    int idx = blockIdx.x * 256 + threadIdx.x;      // 10240: oi = idx>>6, b = idx&63
    float a0 = 0.f, a1 = 0.f, a2 = 0.f, a3 = 0.f;
    for (int k = 0; k < 784; k += 4) {
        a0 += part[(size_t)(k + 0) * 10240 + idx];
        a1 += part[(size_t)(k + 1) * 10240 + idx];
        a2 += part[(size_t)(k + 2) * 10240 + idx];
        a3 += part[(size_t)(k + 3) * 10240 + idx];
    }
    int oi = idx >> 6, b = idx & 63;
    s[b * 160 + oi] = ((a0 + a1) + (a2 + a3)) * scale;
}

// ---------------- squash s -> v ----------------
__global__ void squash_v_kernel(const float* __restrict__ s, float* __restrict__ v) {
    int t = threadIdx.x;
    if (t >= 640) return;
    const float* sp = s + t * 16;
    float val[16]; float msq = 0.f;
    #pragma unroll
    for (int i = 0; i < 16; ++i) { val[i] = sp[i]; msq = fmaf(val[i], val[i], msq); }
    float mag = sqrtf(msq + 1e-9f);
    float sc = msq / (1.f + msq) / (mag + 1e-9f);
    float* vp = v + t * 16;
    #pragma unroll
    for (int i = 0; i < 16; ++i) vp[i] = val[i] * sc;
}

extern "C" void kernel_launch(void* const* d_in, const int* in_sizes, int n_in,
                              void* d_out, int out_size, void* d_ws, size_t ws_size,
                              hipStream_t stream) {
    const float* x  = (const float*)d_in[0];
    const float* w1 = (const float*)d_in[1];
    const float* b1 = (const float*)d_in[2];
    const float* pw = (const float*)d_in[3];
    const float* pb = (const float*)d_in[4];
    const float* W  = (const float*)d_in[5];
    float* out = (float*)d_out;
    float* ws  = (float*)d_ws;

    ushort_t* hb   = (ushort_t*)(ws + HB_OFF);
    ushort_t* wt2  = (ushort_t*)(ws + WT2_OFF);
    float*    tmp  = ws + TMP_OFF;
    float*    ut2  = ws + UT2_OFF;
    float*    s    = ws + S_OFF;
    float*    v0   = ws + V0_OFF;
    float*    v1   = ws + V1_OFF;
    float*    part = ws + PART_OFF;

    conv1_nhwc_kernel<<<dim3(1024, 8), 256, 0, stream>>>(x, w1, b1, hb);
    wt2_transform_kernel<<<1296, 256, 0, stream>>>(pw, wt2);
    conv2_mfma_kernel<<<784, 256, 0, stream>>>(hb, wt2, pb, tmp);
    squash_u_kernel<<<1568, 256, 0, stream>>>(tmp, ut2);

    routing4_kernel<0><<<784, 256, 0, stream>>>(W, ut2, nullptr, nullptr, part);
    reduce_s_kernel<<<40, 256, 0, stream>>>(part, s, 0.1f);
    squash_v_kernel<<<1, 640, 0, stream>>>(s, v0);

    routing4_kernel<1><<<784, 256, 0, stream>>>(W, ut2, v0, nullptr, part);
    reduce_s_kernel<<<40, 256, 0, stream>>>(part, s, 1.f);
    squash_v_kernel<<<1, 640, 0, stream>>>(s, v1);

    routing4_kernel<2><<<784, 256, 0, stream>>>(W, ut2, v0, v1, part);
    reduce_s_kernel<<<40, 256, 0, stream>>>(part, s, 1.f);
    squash_v_kernel<<<1, 640, 0, stream>>>(s, out);
}

// Round 6
// 483.335 us; speedup vs baseline: 4.1760x; 1.1817x over previous
//
#include <hip/hip_runtime.h>
#include <math.h>

typedef unsigned short ushort_t;
typedef __attribute__((ext_vector_type(8))) short bf16x8;
typedef __attribute__((ext_vector_type(4))) float f32x4;
typedef __attribute__((ext_vector_type(8))) unsigned short us8;

typedef __attribute__((address_space(1))) unsigned int gu32;
typedef __attribute__((address_space(3))) unsigned int lu32;

__device__ __forceinline__ void gload16(const void* g, void* l) {
    __builtin_amdgcn_global_load_lds((const gu32*)g, (lu32*)l, 16, 0, 0);
}

__device__ __forceinline__ unsigned short f2bf(float f) {
    unsigned u = __float_as_uint(f);
    unsigned r = ((u >> 16) & 1u) + 0x7fffu;
    return (unsigned short)((u + r) >> 16);
}

// ---------------- workspace layout (float offsets) ----------------
#define HB_OFF   0ULL           // hb  [64][64][64][64] bf16  (8,388,608 slots); Wb overlays after conv2
#define WB_OFF   0ULL           // Wb  [6272][160][8] bf16    (4,014,080 slots)
#define WT2_OFF  8388608ULL     // wt2 [81][64][64] bf16      (165,888 slots)
#define TMP_OFF  8554496ULL     // tmp [64][784][64] f32       3,211,264
#define UTB_OFF  11765760ULL    // utb [6272][64][8] bf16     (1,605,632 slots)
#define S_OFF    13371392ULL
#define V0_OFF   13381632ULL
#define V1_OFF   13391872ULL
#define PART_OFF 13402112ULL    // part [784][160][64] f32     8,028,160  (end 21.4M floats)

// ---------------- conv1: 1->64ch, k5, pad2, +bias, relu -> NHWC bf16 ----------------
__global__ __launch_bounds__(256) void conv1_nhwc_kernel(const float* __restrict__ x,
                                                         const float* __restrict__ w,
                                                         const float* __restrict__ bias,
                                                         ushort_t* __restrict__ hb) {
    int t = blockIdx.x * 256 + threadIdx.x;         // 262144 (b,y,x)
    int xx = t & 63, yy = (t >> 6) & 63, b = t >> 12;
    int cg = blockIdx.y;                            // 0..7
    const float* xb = x + (size_t)b * 4096;
    float xv[25];
    #pragma unroll
    for (int ky = 0; ky < 5; ++ky) {
        int iy = yy + ky - 2;
        #pragma unroll
        for (int kx = 0; kx < 5; ++kx) {
            int ix = xx + kx - 2;
            bool ok = (iy >= 0 && iy < 64 && ix >= 0 && ix < 64);
            xv[ky * 5 + kx] = ok ? xb[iy * 64 + ix] : 0.f;
        }
    }
    us8 o;
    #pragma unroll
    for (int cc = 0; cc < 8; ++cc) {
        int c = cg * 8 + cc;
        float acc = bias[c];
        const float* wc = w + c * 25;
        #pragma unroll
        for (int k = 0; k < 25; ++k) acc = fmaf(xv[k], wc[k], acc);
        o[cc] = f2bf(fmaxf(acc, 0.f));
    }
    *(us8*)&hb[(size_t)t * 64 + cg * 8] = o;
}

// ---------------- conv2 weight transform: pw[c][ic][9][9] f32 -> wt2[p][c][ic] bf16 --------
__global__ __launch_bounds__(256) void wt2_transform_kernel(const float* __restrict__ pw,
                                                            ushort_t* __restrict__ wt2) {
    int t = blockIdx.x * 256 + threadIdx.x;         // 331776
    int ic = t & 63, c = (t >> 6) & 63, p = t >> 12;
    wt2[t] = f2bf(pw[(size_t)(c * 64 + ic) * 81 + p]);
}

// ---------------- conv2 implicit-GEMM MFMA: 64->64, k9, s2, +bias ----------------
__global__ __launch_bounds__(256) void conv2_mfma_kernel(const ushort_t* __restrict__ hb,
                                                         const ushort_t* __restrict__ wt2,
                                                         const float* __restrict__ pb,
                                                         float* __restrict__ tmp) {
    __shared__ ushort_t As[2][4096];
    __shared__ ushort_t Bs[2][4096];

    int tid = threadIdx.x;
    int w = tid >> 6, lane = tid & 63;
    int m0 = blockIdx.x * 64;

    int srow = w * 16 + (lane >> 3);
    int srcchunk = (lane & 7) ^ ((lane >> 3) & 7);
    unsigned gbaseA[2];
    #pragma unroll
    for (int k = 0; k < 2; ++k) {
        int r = srow + k * 8;
        int m = m0 + r;
        int b = m / 784, pos = m % 784;
        int oy = pos / 28, ox = pos % 28;
        gbaseA[k] = ((unsigned)((b * 64 + 2 * oy) * 64 + 2 * ox)) * 64 + srcchunk * 8;
    }
    unsigned gbaseB[2] = { (unsigned)srow * 64 + srcchunk * 8,
                           (unsigned)(srow + 8) * 64 + srcchunk * 8 };

    int fr = lane & 15, fq = lane >> 4;
    int rlow = fr & 7;
    int c0 = (fq ^ rlow) * 8;
    int c1 = ((4 + fq) ^ rlow) * 8;
    int rowA = w * 16 + fr;
    int offA0 = rowA * 64 + c0, offA1 = rowA * 64 + c1;
    int offB0[4], offB1[4];
    #pragma unroll
    for (int jf = 0; jf < 4; ++jf) {
        int rowB = jf * 16 + fr;
        offB0[jf] = rowB * 64 + c0;
        offB1[jf] = rowB * 64 + c1;
    }

    f32x4 acc[4] = {};

    auto stage = [&](int p, int buf) {
        int ky = p / 9, kx = p % 9;
        unsigned koff = (unsigned)(ky * 4096 + kx * 64);
        unsigned boff = (unsigned)p * 4096;
        gload16(hb + gbaseA[0] + koff, &As[buf][w * 1024]);
        gload16(hb + gbaseA[1] + koff, &As[buf][w * 1024 + 512]);
        gload16(wt2 + boff + gbaseB[0], &Bs[buf][w * 1024]);
        gload16(wt2 + boff + gbaseB[1], &Bs[buf][w * 1024 + 512]);
    };

    stage(0, 0);
    __syncthreads();

    for (int p = 0; p < 81; ++p) {
        int cur = p & 1;
        const ushort_t* A = As[cur];
        const ushort_t* B = Bs[cur];
        bf16x8 a0 = *(const bf16x8*)&A[offA0];
        bf16x8 a1 = *(const bf16x8*)&A[offA1];
        bf16x8 b0[4], b1[4];
        #pragma unroll
        for (int jf = 0; jf < 4; ++jf) {
            b0[jf] = *(const bf16x8*)&B[offB0[jf]];
            b1[jf] = *(const bf16x8*)&B[offB1[jf]];
        }
        #pragma unroll
        for (int jf = 0; jf < 4; ++jf)
            acc[jf] = __builtin_amdgcn_mfma_f32_16x16x32_bf16(a0, b0[jf], acc[jf], 0, 0, 0);
        #pragma unroll
        for (int jf = 0; jf < 4; ++jf)
            acc[jf] = __builtin_amdgcn_mfma_f32_16x16x32_bf16(a1, b1[jf], acc[jf], 0, 0, 0);
        if (p < 80) stage(p + 1, cur ^ 1);
        __syncthreads();
    }

    #pragma unroll
    for (int jf = 0; jf < 4; ++jf) {
        int n = jf * 16 + fr;
        float bv = pb[n];
        #pragma unroll
        for (int reg = 0; reg < 4; ++reg) {
            int m = w * 16 + fq * 4 + reg;
            tmp[(size_t)(m0 + m) * 64 + n] = acc[jf][reg] + bv;
        }
    }
}

// ---------------- squash u -> utb[n][b][8] bf16 ----------------
__global__ __launch_bounds__(256) void squash_u_kernel(const float* __restrict__ tmp,
                                                       ushort_t* __restrict__ utb) {
    int idx = blockIdx.x * 256 + threadIdx.x;      // 401,408 = 6272*64
    int b = idx & 63;
    int n = idx >> 6;
    int caps = n / 784, pos = n % 784;
    const float* tp = tmp + ((size_t)b * 784 + pos) * 64 + caps * 8;
    float v[8]; float msq = 0.f;
    #pragma unroll
    for (int j = 0; j < 8; ++j) { v[j] = tp[j]; msq = fmaf(v[j], v[j], msq); }
    float mag = sqrtf(msq + 1e-9f);
    float sc = msq / (1.f + msq) / (mag + 1e-9f);
    us8 o;
    #pragma unroll
    for (int j = 0; j < 8; ++j) o[j] = f2bf(v[j] * sc);
    *(us8*)&utb[(size_t)idx * 8] = o;
}

// ---------------- W -> bf16 copy-cast: Wb[n][160][8] ----------------
__global__ __launch_bounds__(256) void wb_kernel(const float* __restrict__ W,
                                                 ushort_t* __restrict__ Wb) {
    int t = blockIdx.x * 256 + threadIdx.x;        // 1,003,520 threads x 8 elems
    const float* src = W + (size_t)t * 8;
    us8 o;
    #pragma unroll
    for (int j = 0; j < 8; ++j) o[j] = f2bf(src[j]);
    *(us8*)&Wb[(size_t)t * 8] = o;
}

// ---------------- routing via MFMA: block = 8 routes x 64 batches ----------------
// Per route n, per wave (16 batches): u_hat tile = W[n](16i x 8) x u^T(8 x 16b) via
// mfma_f32_16x16x32_bf16 with K zero-padded (fq==0 lanes carry real data).
// C layout: col=lane&15=batch, row=fq*4+reg=i  -> logit sum over i via shfl_xor(16,32).
#define RPB 8
template<int ITER>
__global__ __launch_bounds__(256) void routing5_kernel(const ushort_t* __restrict__ Wb,
                                                       const ushort_t* __restrict__ utb,
                                                       const float* __restrict__ v0,
                                                       const float* __restrict__ v1,
                                                       float* __restrict__ part) {
    __shared__ ushort_t Wl[RPB * 1280];   // 20 KB  [route][oi=o*16+i][8]
    __shared__ ushort_t Ul[RPB * 512];    // 8 KB   [route][batch][8]
    int tid = threadIdx.x;
    int lane = tid & 63;
    int wid = tid >> 6;                   // batch-quad
    int fr = lane & 15, fq = lane >> 4;
    int n0 = blockIdx.x * RPB;
    int b = wid * 16 + fr;

    {   // stage W (1280 chunks) + u (512 chunks), linear LDS
        int w64 = wid * 64;
        const ushort_t* wsrc = Wb + (size_t)n0 * 1280;
        #pragma unroll
        for (int k = 0; k < 5; ++k)
            gload16(wsrc + (size_t)(k * 256 + tid) * 8, &Wl[(k * 256 + w64) * 8]);
        const ushort_t* usrc = utb + (size_t)n0 * 512;
        #pragma unroll
        for (int k = 0; k < 2; ++k)
            gload16(usrc + (size_t)(k * 256 + tid) * 8, &Ul[(k * 256 + w64) * 8]);
    }

    float vsum[40];
    if (ITER >= 1) {
        #pragma unroll
        for (int o = 0; o < 10; ++o) {
            f32x4 a = *(const f32x4*)&v0[b * 160 + o * 16 + fq * 4];
            if (ITER == 2) {
                f32x4 cc = *(const f32x4*)&v1[b * 160 + o * 16 + fq * 4];
                a = a + cc;
            }
            *(f32x4*)&vsum[o * 4] = a;
        }
    }

    __syncthreads();

    float sacc[40];
    #pragma unroll
    for (int q = 0; q < 40; ++q) sacc[q] = 0.f;

    const bf16x8 zf = {};
    const f32x4 zc = {};

    #pragma unroll 1
    for (int t = 0; t < RPB; ++t) {
        bf16x8 bfrag = zf;
        if (fq == 0) bfrag = *(const bf16x8*)&Ul[(t * 64 + b) * 8];

        float c10[10];
        if (ITER >= 1) {
            float l[10];
            #pragma unroll
            for (int o = 0; o < 10; ++o) {
                bf16x8 afrag = zf;
                if (fq == 0) afrag = *(const bf16x8*)&Wl[(t * 160 + o * 16 + fr) * 8];
                f32x4 uh = __builtin_amdgcn_mfma_f32_16x16x32_bf16(afrag, bfrag, zc, 0, 0, 0);
                float lo = uh[0] * vsum[o * 4] + uh[1] * vsum[o * 4 + 1] +
                           uh[2] * vsum[o * 4 + 2] + uh[3] * vsum[o * 4 + 3];
                lo += __shfl_xor(lo, 16);
                lo += __shfl_xor(lo, 32);
                l[o] = lo;
            }
            float m = l[0];
            #pragma unroll
            for (int o = 1; o < 10; ++o) m = fmaxf(m, l[o]);
            float sum = 0.f;
            #pragma unroll
            for (int o = 0; o < 10; ++o) { c10[o] = __expf(l[o] - m); sum += c10[o]; }
            float inv = 1.f / sum;
            #pragma unroll
            for (int o = 0; o < 10; ++o) c10[o] *= inv;
        }

        #pragma unroll
        for (int o = 0; o < 10; ++o) {
            bf16x8 afrag = zf;
            if (fq == 0) afrag = *(const bf16x8*)&Wl[(t * 160 + o * 16 + fr) * 8];
            f32x4 uh = __builtin_amdgcn_mfma_f32_16x16x32_bf16(afrag, bfrag, zc, 0, 0, 0);
            float co = (ITER == 0) ? 1.f : c10[o];
            sacc[o * 4 + 0] = fmaf(co, uh[0], sacc[o * 4 + 0]);
            sacc[o * 4 + 1] = fmaf(co, uh[1], sacc[o * 4 + 1]);
            sacc[o * 4 + 2] = fmaf(co, uh[2], sacc[o * 4 + 2]);
            sacc[o * 4 + 3] = fmaf(co, uh[3], sacc[o * 4 + 3]);
        }
    }

    float* pp = part + (size_t)blockIdx.x * 10240;
    #pragma unroll
    for (int o = 0; o < 10; ++o)
        #pragma unroll
        for (int r = 0; r < 4; ++r)
            pp[(o * 16 + fq * 4 + r) * 64 + b] = sacc[o * 4 + r];
}

// ---------------- reduce partials + squash -> v (fused) ----------------
// grid 10 (= o), block 1024: i = tid>>6, b = tid&63
__global__ __launch_bounds__(1024) void reduce_squash_kernel(const float* __restrict__ part,
                                                             float scale,
                                                             float* __restrict__ v) {
    __shared__ float sv[16][64];
    int tid = threadIdx.x;
    int o = blockIdx.x;
    int i = tid >> 6, b = tid & 63;
    int idx = (o * 16 + i) * 64 + b;
    float a0 = 0.f, a1 = 0.f, a2 = 0.f, a3 = 0.f;
    for (int k = 0; k < 784; k += 4) {
        a0 += part[(size_t)(k + 0) * 10240 + idx];
        a1 += part[(size_t)(k + 1) * 10240 + idx];
        a2 += part[(size_t)(k + 2) * 10240 + idx];
        a3 += part[(size_t)(k + 3) * 10240 + idx];
    }
    float s = ((a0 + a1) + (a2 + a3)) * scale;
    sv[i][b] = s * s;
    __syncthreads();
    float msq = 0.f;
    #pragma unroll
    for (int ii = 0; ii < 16; ++ii) msq += sv[ii][b];
    float mag = sqrtf(msq + 1e-9f);
    float sc = msq / (1.f + msq) / (mag + 1e-9f);
    v[b * 160 + o * 16 + i] = s * sc;
}

extern "C" void kernel_launch(void* const* d_in, const int* in_sizes, int n_in,
                              void* d_out, int out_size, void* d_ws, size_t ws_size,
                              hipStream_t stream) {
    const float* x  = (const float*)d_in[0];
    const float* w1 = (const float*)d_in[1];
    const float* b1 = (const float*)d_in[2];
    const float* pw = (const float*)d_in[3];
    const float* pb = (const float*)d_in[4];
    const float* W  = (const float*)d_in[5];
    float* out = (float*)d_out;
    float* ws  = (float*)d_ws;

    ushort_t* hb   = (ushort_t*)(ws + HB_OFF);
    ushort_t* Wb   = (ushort_t*)(ws + WB_OFF);   // overlays hb after conv2
    ushort_t* wt2  = (ushort_t*)(ws + WT2_OFF);
    float*    tmp  = ws + TMP_OFF;
    ushort_t* utb  = (ushort_t*)(ws + UTB_OFF);
    float*    v0   = ws + V0_OFF;
    float*    v1   = ws + V1_OFF;
    float*    part = ws + PART_OFF;

    conv1_nhwc_kernel<<<dim3(1024, 8), 256, 0, stream>>>(x, w1, b1, hb);
    wt2_transform_kernel<<<1296, 256, 0, stream>>>(pw, wt2);
    conv2_mfma_kernel<<<784, 256, 0, stream>>>(hb, wt2, pb, tmp);
    wb_kernel<<<3920, 256, 0, stream>>>(W, Wb);          // hb dead from here
    squash_u_kernel<<<1568, 256, 0, stream>>>(tmp, utb);

    routing5_kernel<0><<<784, 256, 0, stream>>>(Wb, utb, nullptr, nullptr, part);
    reduce_squash_kernel<<<10, 1024, 0, stream>>>(part, 0.1f, v0);

    routing5_kernel<1><<<784, 256, 0, stream>>>(Wb, utb, v0, nullptr, part);
    reduce_squash_kernel<<<10, 1024, 0, stream>>>(part, 1.f, v1);

    routing5_kernel<2><<<784, 256, 0, stream>>>(Wb, utb, v0, v1, part);
    reduce_squash_kernel<<<10, 1024, 0, stream>>>(part, 1.f, out);
}

// Round 7
// 296.797 us; speedup vs baseline: 6.8007x; 1.6285x over previous
//
#include <hip/hip_runtime.h>
#include <math.h>

typedef unsigned short ushort_t;
typedef __attribute__((ext_vector_type(8))) short bf16x8;
typedef __attribute__((ext_vector_type(4))) float f32x4;
typedef __attribute__((ext_vector_type(8))) unsigned short us8;

typedef __attribute__((address_space(1))) unsigned int gu32;
typedef __attribute__((address_space(3))) unsigned int lu32;

__device__ __forceinline__ void gload16(const void* g, void* l) {
    __builtin_amdgcn_global_load_lds((const gu32*)g, (lu32*)l, 16, 0, 0);
}

__device__ __forceinline__ unsigned short f2bf(float f) {
    unsigned u = __float_as_uint(f);
    unsigned r = ((u >> 16) & 1u) + 0x7fffu;
    return (unsigned short)((u + r) >> 16);
}

// ---------------- workspace layout (float offsets) ----------------
#define HB_OFF    0ULL          // hb  [64][64][64][64] bf16  (8,388,608 slots); Wb overlays after conv2
#define WB_OFF    0ULL          // Wb  [6272][160][8] bf16    (4,014,080 slots)
#define WT2_OFF   8388608ULL    // wt2 [81][64][64] bf16      (165,888 slots)
#define TMP_OFF   8554496ULL    // tmp [64][784][64] f32       3,211,264
#define UTB_OFF   11765760ULL   // utb [6272][64][8] bf16     (1,605,632 slots)
#define S_OFF     13371392ULL
#define V0_OFF    13381632ULL
#define V1_OFF    13391872ULL
#define PART_OFF  13402112ULL   // part  [784][160][64] f32    8,028,160
#define PART2_OFF 21430272ULL   // part2 [16][160][64] f32       163,840

// ---------------- conv1: 1->64ch, k5, pad2, +bias, relu -> NHWC bf16 ----------------
__global__ __launch_bounds__(256) void conv1_nhwc_kernel(const float* __restrict__ x,
                                                         const float* __restrict__ w,
                                                         const float* __restrict__ bias,
                                                         ushort_t* __restrict__ hb) {
    int t = blockIdx.x * 256 + threadIdx.x;         // 262144 (b,y,x)
    int xx = t & 63, yy = (t >> 6) & 63, b = t >> 12;
    int cg = blockIdx.y;                            // 0..7
    const float* xb = x + (size_t)b * 4096;
    float xv[25];
    #pragma unroll
    for (int ky = 0; ky < 5; ++ky) {
        int iy = yy + ky - 2;
        #pragma unroll
        for (int kx = 0; kx < 5; ++kx) {
            int ix = xx + kx - 2;
            bool ok = (iy >= 0 && iy < 64 && ix >= 0 && ix < 64);
            xv[ky * 5 + kx] = ok ? xb[iy * 64 + ix] : 0.f;
        }
    }
    us8 o;
    #pragma unroll
    for (int cc = 0; cc < 8; ++cc) {
        int c = cg * 8 + cc;
        float acc = bias[c];
        const float* wc = w + c * 25;
        #pragma unroll
        for (int k = 0; k < 25; ++k) acc = fmaf(xv[k], wc[k], acc);
        o[cc] = f2bf(fmaxf(acc, 0.f));
    }
    *(us8*)&hb[(size_t)t * 64 + cg * 8] = o;
}

// ---------------- conv2 weight transform: pw[c][ic][9][9] f32 -> wt2[p][c][ic] bf16 --------
__global__ __launch_bounds__(256) void wt2_transform_kernel(const float* __restrict__ pw,
                                                            ushort_t* __restrict__ wt2) {
    int t = blockIdx.x * 256 + threadIdx.x;         // 331776
    int ic = t & 63, c = (t >> 6) & 63, p = t >> 12;
    wt2[t] = f2bf(pw[(size_t)(c * 64 + ic) * 81 + p]);
}

// ---------------- conv2 implicit-GEMM MFMA: 64->64, k9, s2, +bias ----------------
__global__ __launch_bounds__(256) void conv2_mfma_kernel(const ushort_t* __restrict__ hb,
                                                         const ushort_t* __restrict__ wt2,
                                                         const float* __restrict__ pb,
                                                         float* __restrict__ tmp) {
    __shared__ ushort_t As[2][4096];
    __shared__ ushort_t Bs[2][4096];

    int tid = threadIdx.x;
    int w = tid >> 6, lane = tid & 63;
    int m0 = blockIdx.x * 64;

    int srow = w * 16 + (lane >> 3);
    int srcchunk = (lane & 7) ^ ((lane >> 3) & 7);
    unsigned gbaseA[2];
    #pragma unroll
    for (int k = 0; k < 2; ++k) {
        int r = srow + k * 8;
        int m = m0 + r;
        int b = m / 784, pos = m % 784;
        int oy = pos / 28, ox = pos % 28;
        gbaseA[k] = ((unsigned)((b * 64 + 2 * oy) * 64 + 2 * ox)) * 64 + srcchunk * 8;
    }
    unsigned gbaseB[2] = { (unsigned)srow * 64 + srcchunk * 8,
                           (unsigned)(srow + 8) * 64 + srcchunk * 8 };

    int fr = lane & 15, fq = lane >> 4;
    int rlow = fr & 7;
    int c0 = (fq ^ rlow) * 8;
    int c1 = ((4 + fq) ^ rlow) * 8;
    int rowA = w * 16 + fr;
    int offA0 = rowA * 64 + c0, offA1 = rowA * 64 + c1;
    int offB0[4], offB1[4];
    #pragma unroll
    for (int jf = 0; jf < 4; ++jf) {
        int rowB = jf * 16 + fr;
        offB0[jf] = rowB * 64 + c0;
        offB1[jf] = rowB * 64 + c1;
    }

    f32x4 acc[4] = {};

    auto stage = [&](int p, int buf) {
        int ky = p / 9, kx = p % 9;
        unsigned koff = (unsigned)(ky * 4096 + kx * 64);
        unsigned boff = (unsigned)p * 4096;
        gload16(hb + gbaseA[0] + koff, &As[buf][w * 1024]);
        gload16(hb + gbaseA[1] + koff, &As[buf][w * 1024 + 512]);
        gload16(wt2 + boff + gbaseB[0], &Bs[buf][w * 1024]);
        gload16(wt2 + boff + gbaseB[1], &Bs[buf][w * 1024 + 512]);
    };

    stage(0, 0);
    __syncthreads();

    for (int p = 0; p < 81; ++p) {
        int cur = p & 1;
        const ushort_t* A = As[cur];
        const ushort_t* B = Bs[cur];
        bf16x8 a0 = *(const bf16x8*)&A[offA0];
        bf16x8 a1 = *(const bf16x8*)&A[offA1];
        bf16x8 b0[4], b1[4];
        #pragma unroll
        for (int jf = 0; jf < 4; ++jf) {
            b0[jf] = *(const bf16x8*)&B[offB0[jf]];
            b1[jf] = *(const bf16x8*)&B[offB1[jf]];
        }
        #pragma unroll
        for (int jf = 0; jf < 4; ++jf)
            acc[jf] = __builtin_amdgcn_mfma_f32_16x16x32_bf16(a0, b0[jf], acc[jf], 0, 0, 0);
        #pragma unroll
        for (int jf = 0; jf < 4; ++jf)
            acc[jf] = __builtin_amdgcn_mfma_f32_16x16x32_bf16(a1, b1[jf], acc[jf], 0, 0, 0);
        if (p < 80) stage(p + 1, cur ^ 1);
        __syncthreads();
    }

    #pragma unroll
    for (int jf = 0; jf < 4; ++jf) {
        int n = jf * 16 + fr;
        float bv = pb[n];
        #pragma unroll
        for (int reg = 0; reg < 4; ++reg) {
            int m = w * 16 + fq * 4 + reg;
            tmp[(size_t)(m0 + m) * 64 + n] = acc[jf][reg] + bv;
        }
    }
}

// ---------------- squash u -> utb[n][b][8] bf16 ----------------
__global__ __launch_bounds__(256) void squash_u_kernel(const float* __restrict__ tmp,
                                                       ushort_t* __restrict__ utb) {
    int idx = blockIdx.x * 256 + threadIdx.x;      // 401,408 = 6272*64
    int b = idx & 63;
    int n = idx >> 6;
    int caps = n / 784, pos = n % 784;
    const float* tp = tmp + ((size_t)b * 784 + pos) * 64 + caps * 8;
    float v[8]; float msq = 0.f;
    #pragma unroll
    for (int j = 0; j < 8; ++j) { v[j] = tp[j]; msq = fmaf(v[j], v[j], msq); }
    float mag = sqrtf(msq + 1e-9f);
    float sc = msq / (1.f + msq) / (mag + 1e-9f);
    us8 o;
    #pragma unroll
    for (int j = 0; j < 8; ++j) o[j] = f2bf(v[j] * sc);
    *(us8*)&utb[(size_t)idx * 8] = o;
}

// ---------------- W -> bf16 copy-cast: Wb[n][160][8] ----------------
__global__ __launch_bounds__(256) void wb_kernel(const float* __restrict__ W,
                                                 ushort_t* __restrict__ Wb) {
    int t = blockIdx.x * 256 + threadIdx.x;        // 1,003,520 threads x 8 elems
    const float* src = W + (size_t)t * 8;
    us8 o;
    #pragma unroll
    for (int j = 0; j < 8; ++j) o[j] = f2bf(src[j]);
    *(us8*)&Wb[(size_t)t * 8] = o;
}

// ---------------- routing via MFMA: block = 8 routes x 64 batches ----------------
// uh computed ONCE per (route, o) and reused for logits + s-accumulate.
#define RPB 8
template<int ITER>
__global__ __launch_bounds__(256) void routing5_kernel(const ushort_t* __restrict__ Wb,
                                                       const ushort_t* __restrict__ utb,
                                                       const float* __restrict__ v0,
                                                       const float* __restrict__ v1,
                                                       float* __restrict__ part) {
    __shared__ ushort_t Wl[RPB * 1280];   // 20 KB  [route][oi=o*16+i][8]
    __shared__ ushort_t Ul[RPB * 512];    // 8 KB   [route][batch][8]
    int tid = threadIdx.x;
    int lane = tid & 63;
    int wid = tid >> 6;                   // batch-quad
    int fr = lane & 15, fq = lane >> 4;
    int n0 = blockIdx.x * RPB;
    int b = wid * 16 + fr;

    {   // stage W (1280 chunks) + u (512 chunks), linear LDS
        int w64 = wid * 64;
        const ushort_t* wsrc = Wb + (size_t)n0 * 1280;
        #pragma unroll
        for (int k = 0; k < 5; ++k)
            gload16(wsrc + (size_t)(k * 256 + tid) * 8, &Wl[(k * 256 + w64) * 8]);
        const ushort_t* usrc = utb + (size_t)n0 * 512;
        #pragma unroll
        for (int k = 0; k < 2; ++k)
            gload16(usrc + (size_t)(k * 256 + tid) * 8, &Ul[(k * 256 + w64) * 8]);
    }

    float vsum[40];
    if (ITER >= 1) {
        #pragma unroll
        for (int o = 0; o < 10; ++o) {
            f32x4 a = *(const f32x4*)&v0[b * 160 + o * 16 + fq * 4];
            if (ITER == 2) {
                f32x4 cc = *(const f32x4*)&v1[b * 160 + o * 16 + fq * 4];
                a = a + cc;
            }
            *(f32x4*)&vsum[o * 4] = a;
        }
    }

    __syncthreads();

    float sacc[40];
    #pragma unroll
    for (int q = 0; q < 40; ++q) sacc[q] = 0.f;

    const bf16x8 zf = {};
    const f32x4 zc = {};

    #pragma unroll 1
    for (int t = 0; t < RPB; ++t) {
        bf16x8 bfrag = zf;
        if (fq == 0) bfrag = *(const bf16x8*)&Ul[(t * 64 + b) * 8];

        // u_hat for all 10 o's, once (fully unrolled -> static indexing)
        f32x4 uh[10];
        #pragma unroll
        for (int o = 0; o < 10; ++o) {
            bf16x8 afrag = zf;
            if (fq == 0) afrag = *(const bf16x8*)&Wl[(t * 160 + o * 16 + fr) * 8];
            uh[o] = __builtin_amdgcn_mfma_f32_16x16x32_bf16(afrag, bfrag, zc, 0, 0, 0);
        }

        float c10[10];
        if (ITER >= 1) {
            float l[10];
            #pragma unroll
            for (int o = 0; o < 10; ++o) {
                float lo = uh[o][0] * vsum[o * 4] + uh[o][1] * vsum[o * 4 + 1] +
                           uh[o][2] * vsum[o * 4 + 2] + uh[o][3] * vsum[o * 4 + 3];
                lo += __shfl_xor(lo, 16);
                lo += __shfl_xor(lo, 32);
                l[o] = lo;
            }
            float m = l[0];
            #pragma unroll
            for (int o = 1; o < 10; ++o) m = fmaxf(m, l[o]);
            float sum = 0.f;
            #pragma unroll
            for (int o = 0; o < 10; ++o) { c10[o] = __expf(l[o] - m); sum += c10[o]; }
            float inv = 1.f / sum;
            #pragma unroll
            for (int o = 0; o < 10; ++o) c10[o] *= inv;
        }

        #pragma unroll
        for (int o = 0; o < 10; ++o) {
            float co = (ITER == 0) ? 1.f : c10[o];
            sacc[o * 4 + 0] = fmaf(co, uh[o][0], sacc[o * 4 + 0]);
            sacc[o * 4 + 1] = fmaf(co, uh[o][1], sacc[o * 4 + 1]);
            sacc[o * 4 + 2] = fmaf(co, uh[o][2], sacc[o * 4 + 2]);
            sacc[o * 4 + 3] = fmaf(co, uh[o][3], sacc[o * 4 + 3]);
        }
    }

    float* pp = part + (size_t)blockIdx.x * 10240;
    #pragma unroll
    for (int o = 0; o < 10; ++o)
        #pragma unroll
        for (int r = 0; r < 4; ++r)
            pp[(o * 16 + fq * 4 + r) * 64 + b] = sacc[o * 4 + r];
}

// ---------------- reduce stage 1: 784 -> 16 partials ----------------
// grid (40, 16), block 256: sums 49 k-slices into part2[kc][idx]
__global__ __launch_bounds__(256) void reduce_part1_kernel(const float* __restrict__ part,
                                                           float* __restrict__ part2) {
    int idx = blockIdx.x * 256 + threadIdx.x;      // 0..10239
    int kc = blockIdx.y;                           // 0..15
    const float* p = part + (size_t)kc * 49 * 10240 + idx;
    float a0 = 0.f, a1 = 0.f, a2 = 0.f, a3 = 0.f;
    #pragma unroll
    for (int k = 0; k < 48; k += 4) {
        a0 += p[(size_t)(k + 0) * 10240];
        a1 += p[(size_t)(k + 1) * 10240];
        a2 += p[(size_t)(k + 2) * 10240];
        a3 += p[(size_t)(k + 3) * 10240];
    }
    part2[kc * 10240 + idx] = ((a0 + a1) + (a2 + a3)) + p[48ULL * 10240];
}

// ---------------- reduce stage 2 + squash -> v (fused) ----------------
// grid 10 (= o), block 1024: i = tid>>6, b = tid&63
__global__ __launch_bounds__(1024) void reduce_squash_kernel(const float* __restrict__ part2,
                                                             float scale,
                                                             float* __restrict__ v) {
    __shared__ float sv[16][64];
    int tid = threadIdx.x;
    int o = blockIdx.x;
    int i = tid >> 6, b = tid & 63;
    int idx = (o * 16 + i) * 64 + b;
    float a0 = 0.f, a1 = 0.f, a2 = 0.f, a3 = 0.f;
    #pragma unroll
    for (int k = 0; k < 16; k += 4) {
        a0 += part2[(k + 0) * 10240 + idx];
        a1 += part2[(k + 1) * 10240 + idx];
        a2 += part2[(k + 2) * 10240 + idx];
        a3 += part2[(k + 3) * 10240 + idx];
    }
    float s = ((a0 + a1) + (a2 + a3)) * scale;
    sv[i][b] = s * s;
    __syncthreads();
    float msq = 0.f;
    #pragma unroll
    for (int ii = 0; ii < 16; ++ii) msq += sv[ii][b];
    float mag = sqrtf(msq + 1e-9f);
    float sc = msq / (1.f + msq) / (mag + 1e-9f);
    v[b * 160 + o * 16 + i] = s * sc;
}

extern "C" void kernel_launch(void* const* d_in, const int* in_sizes, int n_in,
                              void* d_out, int out_size, void* d_ws, size_t ws_size,
                              hipStream_t stream) {
    const float* x  = (const float*)d_in[0];
    const float* w1 = (const float*)d_in[1];
    const float* b1 = (const float*)d_in[2];
    const float* pw = (const float*)d_in[3];
    const float* pb = (const float*)d_in[4];
    const float* W  = (const float*)d_in[5];
    float* out = (float*)d_out;
    float* ws  = (float*)d_ws;

    ushort_t* hb    = (ushort_t*)(ws + HB_OFF);
    ushort_t* Wb    = (ushort_t*)(ws + WB_OFF);   // overlays hb after conv2
    ushort_t* wt2   = (ushort_t*)(ws + WT2_OFF);
    float*    tmp   = ws + TMP_OFF;
    ushort_t* utb   = (ushort_t*)(ws + UTB_OFF);
    float*    v0    = ws + V0_OFF;
    float*    v1    = ws + V1_OFF;
    float*    part  = ws + PART_OFF;
    float*    part2 = ws + PART2_OFF;

    conv1_nhwc_kernel<<<dim3(1024, 8), 256, 0, stream>>>(x, w1, b1, hb);
    wt2_transform_kernel<<<1296, 256, 0, stream>>>(pw, wt2);
    conv2_mfma_kernel<<<784, 256, 0, stream>>>(hb, wt2, pb, tmp);
    wb_kernel<<<3920, 256, 0, stream>>>(W, Wb);          // hb dead from here
    squash_u_kernel<<<1568, 256, 0, stream>>>(tmp, utb);

    routing5_kernel<0><<<784, 256, 0, stream>>>(Wb, utb, nullptr, nullptr, part);
    reduce_part1_kernel<<<dim3(40, 16), 256, 0, stream>>>(part, part2);
    reduce_squash_kernel<<<10, 1024, 0, stream>>>(part2, 0.1f, v0);

    routing5_kernel<1><<<784, 256, 0, stream>>>(Wb, utb, v0, nullptr, part);
    reduce_part1_kernel<<<dim3(40, 16), 256, 0, stream>>>(part, part2);
    reduce_squash_kernel<<<10, 1024, 0, stream>>>(part2, 1.f, v1);

    routing5_kernel<2><<<784, 256, 0, stream>>>(Wb, utb, v0, v1, part);
    reduce_part1_kernel<<<dim3(40, 16), 256, 0, stream>>>(part, part2);
    reduce_squash_kernel<<<10, 1024, 0, stream>>>(part2, 1.f, out);
}